// Round 8
// baseline (321.982 us; speedup 1.0000x reference)
//
#include <hip/hip_runtime.h>
#include <hip/hip_cooperative_groups.h>
#include <math.h>

namespace cg = cooperative_groups;

#define BB 8
#define LL 32768
#define DD 64
#define GH 16
#define TC 128
#define NC (LL / TC)   /* 256 chunks */
#define BD (BB * DD)   /* 512 chains */
#define WIN 16
#define PAD 8
#define TBLK 512       /* timesteps per block in fused kernel */
#define NBLK 512       /* fused grid: 8 b * 64 tile = 512 blocks, 2/CU */

typedef float f32x2 __attribute__((ext_vector_type(2)));

__device__ __forceinline__ float sig_(float z) { return 1.0f / (1.0f + expf(-z)); }

__device__ __forceinline__ float raw_gate(float xv, const float* w1, const float* bb1,
                                          const float* w2, float bb2) {
    float h = bb2;
#pragma unroll
    for (int i = 0; i < GH; i++) {
        const float z = xv * w1[i] + bb1[i];
        h += (z * sig_(z)) * w2[i];           // silu
    }
    return sig_(h);
}

__device__ __forceinline__ void chan_params(const float* omega, const float* raw_alpha,
                                            int d, float& ar, float& ai) {
    const float alpha = -log1pf(expf(raw_alpha[d]));  // -softplus
    const float r = expf(alpha);
    ar = r * cosf(omega[d]);
    ai = r * sinf(omega[d]);
}

// ================= FUSED cooperative kernel =================
// block k: b = k>>6, tile c4 = k&63 -> timesteps [c4*512, c4*512+512)
// wave wv (0..3) owns chunk c = c4*4+wv (128 steps); lane = channel d.
// ps MUST be BD*NC float4 (2 MiB), hin BD*NC float2 (1 MiB) — disjoint!
template <bool CPLX>
__global__ __launch_bounds__(256, 2) void fused_kernel(
        const float* __restrict__ x,
        const float* __restrict__ omega, const float* __restrict__ raw_alpha,
        const float* __restrict__ b_real, const float* __restrict__ b_imag,
        const float* __restrict__ W1, const float* __restrict__ b1,
        const float* __restrict__ W2, const float* __restrict__ b2,
        float4* __restrict__ ps, float2* __restrict__ hin,
        float* __restrict__ out) {
    __shared__ float xt[TBLK + WIN];    // x[t0-8 .. t0+519]
    __shared__ float sraw[TBLK + WIN];  // raw gate, same range
    __shared__ float gsm[TBLK];         // smoothed gate [t0 .. t0+512)

    const int k    = blockIdx.x;
    const int b    = k >> 6;
    const int c4   = k & 63;
    const int t0   = c4 * TBLK;
    const int tid  = threadIdx.x;
    const int lane = tid & 63;
    const int wv   = tid >> 6;

    // ---- phase 1: gate MLP + box smoothing into LDS ----
    {
        float w1[GH], bb1[GH], w2[GH];
#pragma unroll
        for (int i = 0; i < GH; i++) { w1[i] = W1[i]; bb1[i] = b1[i]; w2[i] = W2[i]; }
        const float bb2 = b2[0];
        for (int j = tid; j < TBLK + WIN; j += 256) {
            int idx = t0 - PAD + j;
            if (idx < 0)   idx = -idx;               // reflect (edge-excluding)
            if (idx >= LL) idx = 2 * LL - 2 - idx;
            const float xv = x[b * LL + idx];
            xt[j] = xv;                              // interior j (8..519) is true x
            sraw[j] = raw_gate(xv, w1, bb1, w2, bb2);
        }
    }
    __syncthreads();
    for (int i = tid; i < TBLK; i += 256) {
        float acc = 0.0f;
#pragma unroll
        for (int kk = 0; kk < WIN; kk++) acc += sraw[i + kk];
        gsm[i] = acc * (1.0f / WIN);
    }
    __syncthreads();

    float ar, ai;
    chan_params(omega, raw_alpha, lane, ar, ai);
    const float br = b_real[lane], bi = b_imag[lane];

    // ---- phase 2: chunk composite (P,S) for chunk c = c4*4+wv ----
    {
        float Pr = 1.0f, Pi = 0.0f, Sr = 0.0f, Si = 0.0f;
        const int lo = wv * TC;
#pragma unroll 4
        for (int t = 0; t < TC; t++) {
            const float g  = gsm[lo + t];
            const float xv = xt[lo + t + PAD];
            const float cr = g * ar, ci = g * ai;
            const float nPr = cr * Pr - ci * Pi;
            const float nPi = cr * Pi + ci * Pr;
            const float nSr = cr * Sr - ci * Si + br * xv;
            const float nSi = cr * Si + ci * Sr + bi * xv;
            Pr = nPr; Pi = nPi; Sr = nSr; Si = nSi;
        }
        const int c = c4 * 4 + wv;
        ps[(b * DD + lane) * NC + c] = make_float4(Pr, Pi, Sr, Si);
    }
    __threadfence();
    cg::this_grid().sync();

    // ---- phase 3: carry scan, one wave per chain (first 128 blocks) ----
    if (k < 128) {
        const int w  = k * 4 + wv;          // chain (b*64+d)
        const int c0 = lane * 4;
        float4 v[4];
#pragma unroll
        for (int j = 0; j < 4; j++) v[j] = ps[w * NC + c0 + j];

        float Pr = 1.0f, Pi = 0.0f, Sr = 0.0f, Si = 0.0f;
#pragma unroll
        for (int j = 0; j < 4; j++) {
            const float pr = v[j].x, pi = v[j].y, sr = v[j].z, si = v[j].w;
            const float nPr = pr * Pr - pi * Pi;
            const float nPi = pr * Pi + pi * Pr;
            const float nSr = pr * Sr - pi * Si + sr;
            const float nSi = pr * Si + pi * Sr + si;
            Pr = nPr; Pi = nPi; Sr = nSr; Si = nSi;
        }
#pragma unroll
        for (int off = 1; off < 64; off <<= 1) {
            const float pPr = __shfl_up(Pr, off, 64);
            const float pPi = __shfl_up(Pi, off, 64);
            const float pSr = __shfl_up(Sr, off, 64);
            const float pSi = __shfl_up(Si, off, 64);
            if (lane >= off) {
                const float nPr = Pr * pPr - Pi * pPi;
                const float nPi = Pr * pPi + Pi * pPr;
                const float nSr = Pr * pSr - Pi * pSi + Sr;
                const float nSi = Pr * pSi + Pi * pSr + Si;
                Pr = nPr; Pi = nPi; Sr = nSr; Si = nSi;
            }
        }
        float hr = __shfl_up(Sr, 1, 64);
        float hi = __shfl_up(Si, 1, 64);
        if (lane == 0) { hr = 0.0f; hi = 0.0f; }
#pragma unroll
        for (int j = 0; j < 4; j++) {
            hin[(c0 + j) * BD + w] = make_float2(hr, hi);
            const float pr = v[j].x, pi = v[j].y, sr = v[j].z, si = v[j].w;
            const float nhr = pr * hr - pi * hi + sr;
            const float nhi = pr * hi + pi * hr + si;
            hr = nhr; hi = nhi;
        }
    }
    __threadfence();
    cg::this_grid().sync();

    // ---- phase 4: expand from carry, stream output ----
    {
        const int c = c4 * 4 + wv;
        const float2 h0 = hin[c * BD + b * DD + lane];
        float hr = h0.x, hi = h0.y;
        const int lo = wv * TC;
        size_t e = (size_t)(b * LL + t0 + lo) * DD + lane;
#pragma unroll 4
        for (int t = 0; t < TC; t++) {
            const float g  = gsm[lo + t];
            const float xv = xt[lo + t + PAD];
            const float cr = g * ar, ci = g * ai;
            const float nhr = cr * hr - ci * hi + br * xv;
            const float nhi = cr * hi + ci * hr + bi * xv;
            hr = nhr; hi = nhi;
            if constexpr (CPLX) {
                f32x2 val; val.x = hr; val.y = hi;
                __builtin_nontemporal_store(val, (f32x2*)out + e);
            } else {
                __builtin_nontemporal_store(hr, out + e);
            }
            e += DD;
        }
    }
}

// ================= Proven 4-kernel fallback path =================
__global__ __launch_bounds__(256) void gate_kernel(
        const float* __restrict__ x,
        const float* __restrict__ W1, const float* __restrict__ b1,
        const float* __restrict__ W2, const float* __restrict__ b2,
        float* __restrict__ gw) {
    __shared__ float sraw[256 + WIN];
    const int tilesPerB = LL / 256;
    const int b  = blockIdx.x / tilesPerB;
    const int t0 = (blockIdx.x % tilesPerB) * 256;

    float w1[GH], bb1[GH], w2[GH];
#pragma unroll
    for (int i = 0; i < GH; i++) { w1[i] = W1[i]; bb1[i] = b1[i]; w2[i] = W2[i]; }
    const float bb2 = b2[0];

    for (int j = threadIdx.x; j < 256 + WIN; j += 256) {
        int idx = t0 - PAD + j;
        if (idx < 0)    idx = -idx;
        if (idx >= LL)  idx = 2 * LL - 2 - idx;
        sraw[j] = raw_gate(x[b * LL + idx], w1, bb1, w2, bb2);
    }
    __syncthreads();

    float acc = 0.0f;
#pragma unroll
    for (int k = 0; k < WIN; k++) acc += sraw[threadIdx.x + k];
    gw[b * LL + t0 + threadIdx.x] = acc * (1.0f / WIN);
}

__global__ __launch_bounds__(256) void chunk_reduce_kernel(
        const float* __restrict__ x, const float* __restrict__ gw,
        const float* __restrict__ omega, const float* __restrict__ raw_alpha,
        const float* __restrict__ b_real, const float* __restrict__ b_imag,
        float4* __restrict__ ps) {
    const int tid = blockIdx.x * blockDim.x + threadIdx.x;
    const int d = tid & (DD - 1);
    const int u = tid >> 6;
    const int b = u / NC;
    const int c = u % NC;

    float ar, ai;
    chan_params(omega, raw_alpha, d, ar, ai);
    const float br = b_real[d], bi = b_imag[d];

    float Pr = 1.0f, Pi = 0.0f, Sr = 0.0f, Si = 0.0f;
    const float4* xb4 = (const float4*)(x  + b * LL + c * TC);
    const float4* gb4 = (const float4*)(gw + b * LL + c * TC);
#pragma unroll 2
    for (int q = 0; q < TC / 4; q++) {
        const float4 g4 = gb4[q];
        const float4 x4 = xb4[q];
        const float gs[4] = {g4.x, g4.y, g4.z, g4.w};
        const float xs[4] = {x4.x, x4.y, x4.z, x4.w};
#pragma unroll
        for (int j = 0; j < 4; j++) {
            const float cr = gs[j] * ar, ci = gs[j] * ai;
            const float nPr = cr * Pr - ci * Pi;
            const float nPi = cr * Pi + ci * Pr;
            const float nSr = cr * Sr - ci * Si + br * xs[j];
            const float nSi = cr * Si + ci * Sr + bi * xs[j];
            Pr = nPr; Pi = nPi; Sr = nSr; Si = nSi;
        }
    }
    ps[(b * DD + d) * NC + c] = make_float4(Pr, Pi, Sr, Si);
}

__global__ __launch_bounds__(256) void carry_scan_kernel(
        const float4* __restrict__ ps, float2* __restrict__ hin) {
    const int w    = blockIdx.x * (blockDim.x >> 6) + (threadIdx.x >> 6);
    const int lane = threadIdx.x & 63;
    const int c0   = lane * 4;

    float4 v[4];
#pragma unroll
    for (int j = 0; j < 4; j++) v[j] = ps[w * NC + c0 + j];

    float Pr = 1.0f, Pi = 0.0f, Sr = 0.0f, Si = 0.0f;
#pragma unroll
    for (int j = 0; j < 4; j++) {
        const float pr = v[j].x, pi = v[j].y, sr = v[j].z, si = v[j].w;
        const float nPr = pr * Pr - pi * Pi;
        const float nPi = pr * Pi + pi * Pr;
        const float nSr = pr * Sr - pi * Si + sr;
        const float nSi = pr * Si + pi * Sr + si;
        Pr = nPr; Pi = nPi; Sr = nSr; Si = nSi;
    }
#pragma unroll
    for (int off = 1; off < 64; off <<= 1) {
        const float pPr = __shfl_up(Pr, off, 64);
        const float pPi = __shfl_up(Pi, off, 64);
        const float pSr = __shfl_up(Sr, off, 64);
        const float pSi = __shfl_up(Si, off, 64);
        if (lane >= off) {
            const float nPr = Pr * pPr - Pi * pPi;
            const float nPi = Pr * pPi + Pi * pPr;
            const float nSr = Pr * pSr - Pi * pSi + Sr;
            const float nSi = Pr * pSi + Pi * pSr + Si;
            Pr = nPr; Pi = nPi; Sr = nSr; Si = nSi;
        }
    }
    float hr = __shfl_up(Sr, 1, 64);
    float hi = __shfl_up(Si, 1, 64);
    if (lane == 0) { hr = 0.0f; hi = 0.0f; }
#pragma unroll
    for (int j = 0; j < 4; j++) {
        hin[(c0 + j) * BD + w] = make_float2(hr, hi);
        const float pr = v[j].x, pi = v[j].y, sr = v[j].z, si = v[j].w;
        const float nhr = pr * hr - pi * hi + sr;
        const float nhi = pr * hi + pi * hr + si;
        hr = nhr; hi = nhi;
    }
}

template <bool CPLX>
__global__ __launch_bounds__(256) void expand_kernel(
        const float* __restrict__ x, const float* __restrict__ gw,
        const float* __restrict__ omega, const float* __restrict__ raw_alpha,
        const float* __restrict__ b_real, const float* __restrict__ b_imag,
        const float2* __restrict__ hin, float* __restrict__ out) {
    const int tid = blockIdx.x * blockDim.x + threadIdx.x;
    const int d = tid & (DD - 1);
    const int u = tid >> 6;
    const int b = u / NC;
    const int c = u % NC;

    float ar, ai;
    chan_params(omega, raw_alpha, d, ar, ai);
    const float br = b_real[d], bi = b_imag[d];

    const float2 h0 = hin[c * BD + (b * DD + d)];
    float hr = h0.x, hi = h0.y;

    const float4* xb4 = (const float4*)(x  + b * LL + c * TC);
    const float4* gb4 = (const float4*)(gw + b * LL + c * TC);
    const size_t base = (size_t)(b * LL + c * TC) * DD + d;

#pragma unroll 2
    for (int q = 0; q < TC / 4; q++) {
        const float4 g4 = gb4[q];
        const float4 x4 = xb4[q];
        const float gs[4] = {g4.x, g4.y, g4.z, g4.w};
        const float xs[4] = {x4.x, x4.y, x4.z, x4.w};
#pragma unroll
        for (int j = 0; j < 4; j++) {
            const float cr = gs[j] * ar, ci = gs[j] * ai;
            const float nhr = cr * hr - ci * hi + br * xs[j];
            const float nhi = cr * hi + ci * hr + bi * xs[j];
            hr = nhr; hi = nhi;
            const size_t e = base + (size_t)(q * 4 + j) * DD;
            if constexpr (CPLX) {
                f32x2 val; val.x = hr; val.y = hi;
                __builtin_nontemporal_store(val, (f32x2*)out + e);
            } else {
                __builtin_nontemporal_store(hr, out + e);
            }
        }
    }
}

// Zero-scratch serial fallback
template <bool CPLX>
__global__ __launch_bounds__(64) void fallback_kernel(
        const float* __restrict__ x,
        const float* __restrict__ omega, const float* __restrict__ raw_alpha,
        const float* __restrict__ b_real, const float* __restrict__ b_imag,
        const float* __restrict__ W1, const float* __restrict__ b1,
        const float* __restrict__ W2, const float* __restrict__ b2,
        float* __restrict__ out) {
    const int b = blockIdx.x;
    const int d = threadIdx.x;

    __shared__ float xtile[64];
    __shared__ float sraw[64 + WIN];
    __shared__ float gsm[64];

    float w1[GH], bb1[GH], w2[GH];
#pragma unroll
    for (int i = 0; i < GH; i++) { w1[i] = W1[i]; bb1[i] = b1[i]; w2[i] = W2[i]; }
    const float bb2 = b2[0];

    float ar, ai;
    chan_params(omega, raw_alpha, d, ar, ai);
    const float br = b_real[d], bi = b_imag[d];

    float hr = 0.0f, hi = 0.0f;
    for (int t0 = 0; t0 < LL; t0 += 64) {
        __syncthreads();
        for (int j = threadIdx.x; j < 64 + WIN; j += 64) {
            int idx = t0 - PAD + j;
            if (idx < 0)   idx = -idx;
            if (idx >= LL) idx = 2 * LL - 2 - idx;
            sraw[j] = raw_gate(x[b * LL + idx], w1, bb1, w2, bb2);
        }
        xtile[threadIdx.x] = x[b * LL + t0 + threadIdx.x];
        __syncthreads();
        float acc = 0.0f;
#pragma unroll
        for (int k = 0; k < WIN; k++) acc += sraw[threadIdx.x + k];
        gsm[threadIdx.x] = acc * (1.0f / WIN);
        __syncthreads();
        for (int tt = 0; tt < 64; tt++) {
            const float g  = gsm[tt];
            const float xv = xtile[tt];
            const float cr = g * ar, ci = g * ai;
            const float nhr = cr * hr - ci * hi + br * xv;
            const float nhi = cr * hi + ci * hr + bi * xv;
            hr = nhr; hi = nhi;
            const size_t e = (size_t)(b * LL + t0 + tt) * DD + d;
            if constexpr (CPLX) {
                f32x2 val; val.x = hr; val.y = hi;
                ((f32x2*)out)[e] = val;
            } else {
                out[e] = hr;
            }
        }
    }
}

extern "C" void kernel_launch(void* const* d_in, const int* in_sizes, int n_in,
                              void* d_out, int out_size, void* d_ws, size_t ws_size,
                              hipStream_t stream) {
    const float* x         = (const float*)d_in[0];
    const float* omega     = (const float*)d_in[1];
    const float* raw_alpha = (const float*)d_in[2];
    const float* b_real    = (const float*)d_in[3];
    const float* b_imag    = (const float*)d_in[4];
    const float* W1        = (const float*)d_in[5];
    const float* b1        = (const float*)d_in[6];
    const float* W2        = (const float*)d_in[7];
    const float* b2        = (const float*)d_in[8];

    float* out = (float*)d_out;

    const long long NOUT = (long long)BB * LL * DD;
    const bool cplx = ((long long)out_size == 2 * NOUT);

    // ---- preferred: fused cooperative kernel (1 dispatch, 2 grid syncs) ----
    // scratch: ps = BD*NC float4 (2 MiB) | hin = BD*NC float2 (1 MiB)  — DISJOINT.
    const size_t PS_BYTES  = (size_t)BD * NC * sizeof(float4);
    const size_t HIN_BYTES = (size_t)BD * NC * sizeof(float2);
    if (ws_size >= PS_BYTES + HIN_BYTES) {
        float4* ps  = (float4*)d_ws;
        float2* hin = (float2*)((char*)d_ws + PS_BYTES);
        void* args[] = {(void*)&x, (void*)&omega, (void*)&raw_alpha, (void*)&b_real,
                        (void*)&b_imag, (void*)&W1, (void*)&b1, (void*)&W2, (void*)&b2,
                        (void*)&ps, (void*)&hin, (void*)&out};
        const void* fn = cplx ? (const void*)&fused_kernel<true>
                              : (const void*)&fused_kernel<false>;
        hipError_t err = hipLaunchCooperativeKernel(fn, dim3(NBLK), dim3(256),
                                                    args, 0, stream);
        if (err == hipSuccess) return;   // deterministic per-environment branch
        (void)hipGetLastError();         // clear sticky error, fall through
    }

    // ---- fallback: proven 4-kernel chunked-scan path ----
    const size_t WSNEED = (size_t)BB * LL * 4 + (size_t)BD * NC * 16 + (size_t)BD * NC * 8;
    if (ws_size >= WSNEED) {
        float*  ws  = (float*)d_ws;
        float*  gw  = ws;
        float4* ps  = (float4*)(ws + BB * LL);
        float2* hin = (float2*)(ws + BB * LL + BD * NC * 4);

        gate_kernel<<<BB * (LL / 256), 256, 0, stream>>>(x, W1, b1, W2, b2, gw);
        chunk_reduce_kernel<<<(BD * NC) / 256, 256, 0, stream>>>(x, gw, omega, raw_alpha,
                                                                 b_real, b_imag, ps);
        carry_scan_kernel<<<BD / 4, 256, 0, stream>>>(ps, hin);
        if (cplx) {
            expand_kernel<true><<<(BD * NC) / 256, 256, 0, stream>>>(
                x, gw, omega, raw_alpha, b_real, b_imag, hin, out);
        } else {
            expand_kernel<false><<<(BD * NC) / 256, 256, 0, stream>>>(
                x, gw, omega, raw_alpha, b_real, b_imag, hin, out);
        }
    } else {
        if (cplx) {
            fallback_kernel<true><<<BB, 64, 0, stream>>>(
                x, omega, raw_alpha, b_real, b_imag, W1, b1, W2, b2, out);
        } else {
            fallback_kernel<false><<<BB, 64, 0, stream>>>(
                x, omega, raw_alpha, b_real, b_imag, W1, b1, W2, b2, out);
        }
    }
}

// Round 9
// 198.529 us; speedup vs baseline: 1.6218x; 1.6218x over previous
//
#include <hip/hip_runtime.h>
#include <math.h>

#define BB 8
#define LL 32768
#define DD 64
#define GH 16
#define TC 128
#define NC (LL / TC)          /* 256 chunks per sequence */
#define BD (BB * DD)          /* 512 chains */
#define WIN 16
#define PAD 8
#define WPB 4                 /* waves per block */
#define NBLK (BB * NC / WPB)  /* 512 blocks, 64 per batch b */

typedef float f32x2 __attribute__((ext_vector_type(2)));

__device__ __forceinline__ float sig_(float z) { return 1.0f / (1.0f + expf(-z)); }

__device__ __forceinline__ float raw_gate(float xv, const float* w1, const float* bb1,
                                          const float* w2, float bb2) {
    float h = bb2;
#pragma unroll
    for (int i = 0; i < GH; i++) {
        const float z = xv * w1[i] + bb1[i];
        h += (z * sig_(z)) * w2[i];           // silu
    }
    return sig_(h);
}

__device__ __forceinline__ void chan_params(const float* omega, const float* raw_alpha,
                                            int d, float& ar, float& ai) {
    const float alpha = -log1pf(expf(raw_alpha[d]));  // -softplus
    const float r = expf(alpha);
    ar = r * cosf(omega[d]);
    ai = r * sinf(omega[d]);
}

// Stage gate (smoothed) + x for chunk (b,c) into this wave's LDS slices.
// Wave-synchronous: no __syncthreads needed (wave64 lockstep, compiler waits lgkm).
__device__ __forceinline__ void stage_gate_x(
        const float* __restrict__ x, int b, int t0, int lane,
        const float* __restrict__ W1, const float* __restrict__ b1,
        const float* __restrict__ W2, const float* __restrict__ b2,
        float* __restrict__ sraw, float* __restrict__ gsm, float* __restrict__ xt) {
    float w1[GH], bb1[GH], w2[GH];
#pragma unroll
    for (int i = 0; i < GH; i++) { w1[i] = W1[i]; bb1[i] = b1[i]; w2[i] = W2[i]; }
    const float bb2 = b2[0];
    for (int j = lane; j < TC + WIN; j += 64) {
        int idx = t0 - PAD + j;
        if (idx < 0)   idx = -idx;               // reflect (edge-excluding)
        if (idx >= LL) idx = 2 * LL - 2 - idx;
        const float xv = x[b * LL + idx];
        sraw[j] = raw_gate(xv, w1, bb1, w2, bb2);
        if (j >= PAD && j < PAD + TC) xt[j - PAD] = xv;
    }
    for (int i = lane; i < TC; i += 64) {
        float acc = 0.0f;
#pragma unroll
        for (int k = 0; k < WIN; k++) acc += sraw[i + k];
        gsm[i] = acc * (1.0f / WIN);
    }
}

// ---------- K1: chunk composites + last-block-per-batch carry scan ----------
// ps layout [c][chain] (coalesced write); hin layout [c][chain] (coalesced K2 read)
__global__ __launch_bounds__(256) void reduce_carry_kernel(
        const float* __restrict__ x,
        const float* __restrict__ omega, const float* __restrict__ raw_alpha,
        const float* __restrict__ b_real, const float* __restrict__ b_imag,
        const float* __restrict__ W1, const float* __restrict__ b1,
        const float* __restrict__ W2, const float* __restrict__ b2,
        float4* __restrict__ ps, float2* __restrict__ hin,
        unsigned int* __restrict__ ctr) {
    __shared__ float sraw[WPB][TC + WIN];
    __shared__ float gsm[WPB][TC];
    __shared__ float xt[WPB][TC];
    __shared__ int lastflag;

    const int tid  = threadIdx.x;
    const int lane = tid & 63;
    const int wv   = tid >> 6;
    const int u    = blockIdx.x * WPB + wv;   // (b, c); all 4 waves share b
    const int b    = u / NC;
    const int c    = u & (NC - 1);
    const int t0   = c * TC;

    stage_gate_x(x, b, t0, lane, W1, b1, W2, b2, sraw[wv], gsm[wv], xt[wv]);

    float ar, ai;
    chan_params(omega, raw_alpha, lane, ar, ai);
    const float br = b_real[lane], bi = b_imag[lane];

    float Pr = 1.0f, Pi = 0.0f, Sr = 0.0f, Si = 0.0f;
#pragma unroll 4
    for (int t = 0; t < TC; t++) {
        const float g  = gsm[wv][t];
        const float xv = xt[wv][t];
        const float cr = g * ar, ci = g * ai;
        const float nPr = cr * Pr - ci * Pi;
        const float nPi = cr * Pi + ci * Pr;
        const float nSr = cr * Sr - ci * Si + br * xv;
        const float nSi = cr * Si + ci * Sr + bi * xv;
        Pr = nPr; Pi = nPi; Sr = nSr; Si = nSi;
    }
    ps[c * BD + b * DD + lane] = make_float4(Pr, Pi, Sr, Si);

    // completion protocol: release fence -> count; 64th block of b does carry scan
    __threadfence();
    __syncthreads();
    if (tid == 0) lastflag = (atomicAdd(&ctr[b], 1u) == 63u) ? 1 : 0;
    __syncthreads();
    if (lastflag) {
        __threadfence();                      // acquire: see all blocks' ps
        for (int dd = wv * 16; dd < wv * 16 + 16; dd++) {
            const int chain = b * DD + dd;
            const int c0 = lane * 4;          // 4 chunks per lane
            float4 v[4];
#pragma unroll
            for (int j = 0; j < 4; j++) v[j] = ps[(c0 + j) * BD + chain];

            float Qr = 1.0f, Qi = 0.0f, Tr = 0.0f, Ti = 0.0f;
#pragma unroll
            for (int j = 0; j < 4; j++) {
                const float pr = v[j].x, pi = v[j].y, sr = v[j].z, si = v[j].w;
                const float nQr = pr * Qr - pi * Qi;
                const float nQi = pr * Qi + pi * Qr;
                const float nTr = pr * Tr - pi * Ti + sr;
                const float nTi = pr * Ti + pi * Tr + si;
                Qr = nQr; Qi = nQi; Tr = nTr; Ti = nTi;
            }
#pragma unroll
            for (int off = 1; off < 64; off <<= 1) {
                const float pQr = __shfl_up(Qr, off, 64);
                const float pQi = __shfl_up(Qi, off, 64);
                const float pTr = __shfl_up(Tr, off, 64);
                const float pTi = __shfl_up(Ti, off, 64);
                if (lane >= off) {
                    const float nQr = Qr * pQr - Qi * pQi;
                    const float nQi = Qr * pQi + Qi * pQr;
                    const float nTr = Qr * pTr - Qi * pTi + Tr;
                    const float nTi = Qr * pTi + Qi * pTr + Ti;
                    Qr = nQr; Qi = nQi; Tr = nTr; Ti = nTi;
                }
            }
            float hr = __shfl_up(Tr, 1, 64);
            float hi = __shfl_up(Ti, 1, 64);
            if (lane == 0) { hr = 0.0f; hi = 0.0f; }
#pragma unroll
            for (int j = 0; j < 4; j++) {
                hin[(c0 + j) * BD + chain] = make_float2(hr, hi);
                const float pr = v[j].x, pi = v[j].y, sr = v[j].z, si = v[j].w;
                const float nhr = pr * hr - pi * hi + sr;
                const float nhi = pr * hi + pi * hr + si;
                hr = nhr; hi = nhi;
            }
        }
    }
}

// ---------- K2: expand from carries, stream output ----------
template <bool CPLX>
__global__ __launch_bounds__(256) void expand2_kernel(
        const float* __restrict__ x,
        const float* __restrict__ omega, const float* __restrict__ raw_alpha,
        const float* __restrict__ b_real, const float* __restrict__ b_imag,
        const float* __restrict__ W1, const float* __restrict__ b1,
        const float* __restrict__ W2, const float* __restrict__ b2,
        const float2* __restrict__ hin, float* __restrict__ out) {
    __shared__ float sraw[WPB][TC + WIN];
    __shared__ float gsm[WPB][TC];
    __shared__ float xt[WPB][TC];

    const int tid  = threadIdx.x;
    const int lane = tid & 63;
    const int wv   = tid >> 6;
    const int u    = blockIdx.x * WPB + wv;
    const int b    = u / NC;
    const int c    = u & (NC - 1);
    const int t0   = c * TC;

    stage_gate_x(x, b, t0, lane, W1, b1, W2, b2, sraw[wv], gsm[wv], xt[wv]);

    float ar, ai;
    chan_params(omega, raw_alpha, lane, ar, ai);
    const float br = b_real[lane], bi = b_imag[lane];

    const float2 h0 = hin[c * BD + b * DD + lane];
    float hr = h0.x, hi = h0.y;

    size_t e = (size_t)(b * LL + t0) * DD + lane;
#pragma unroll 4
    for (int t = 0; t < TC; t++) {
        const float g  = gsm[wv][t];
        const float xv = xt[wv][t];
        const float cr = g * ar, ci = g * ai;
        const float nhr = cr * hr - ci * hi + br * xv;
        const float nhi = cr * hi + ci * hr + bi * xv;
        hr = nhr; hi = nhi;
        if constexpr (CPLX) {
            f32x2 val; val.x = hr; val.y = hi;
            __builtin_nontemporal_store(val, (f32x2*)out + e);
        } else {
            __builtin_nontemporal_store(hr, out + e);
        }
        e += DD;
    }
}

// ---------- zero-scratch serial fallback (insurance) ----------
template <bool CPLX>
__global__ __launch_bounds__(64) void fallback_kernel(
        const float* __restrict__ x,
        const float* __restrict__ omega, const float* __restrict__ raw_alpha,
        const float* __restrict__ b_real, const float* __restrict__ b_imag,
        const float* __restrict__ W1, const float* __restrict__ b1,
        const float* __restrict__ W2, const float* __restrict__ b2,
        float* __restrict__ out) {
    const int b = blockIdx.x;
    const int d = threadIdx.x;

    __shared__ float xtile[64];
    __shared__ float sraw[64 + WIN];
    __shared__ float gsm[64];

    float w1[GH], bb1[GH], w2[GH];
#pragma unroll
    for (int i = 0; i < GH; i++) { w1[i] = W1[i]; bb1[i] = b1[i]; w2[i] = W2[i]; }
    const float bb2 = b2[0];

    float ar, ai;
    chan_params(omega, raw_alpha, d, ar, ai);
    const float br = b_real[d], bi = b_imag[d];

    float hr = 0.0f, hi = 0.0f;
    for (int t0 = 0; t0 < LL; t0 += 64) {
        __syncthreads();
        for (int j = threadIdx.x; j < 64 + WIN; j += 64) {
            int idx = t0 - PAD + j;
            if (idx < 0)   idx = -idx;
            if (idx >= LL) idx = 2 * LL - 2 - idx;
            sraw[j] = raw_gate(x[b * LL + idx], w1, bb1, w2, bb2);
        }
        xtile[threadIdx.x] = x[b * LL + t0 + threadIdx.x];
        __syncthreads();
        float acc = 0.0f;
#pragma unroll
        for (int k = 0; k < WIN; k++) acc += sraw[threadIdx.x + k];
        gsm[threadIdx.x] = acc * (1.0f / WIN);
        __syncthreads();
        for (int tt = 0; tt < 64; tt++) {
            const float g  = gsm[tt];
            const float xv = xtile[tt];
            const float cr = g * ar, ci = g * ai;
            const float nhr = cr * hr - ci * hi + br * xv;
            const float nhi = cr * hi + ci * hr + bi * xv;
            hr = nhr; hi = nhi;
            const size_t e = (size_t)(b * LL + t0 + tt) * DD + d;
            if constexpr (CPLX) {
                f32x2 val; val.x = hr; val.y = hi;
                ((f32x2*)out)[e] = val;
            } else {
                out[e] = hr;
            }
        }
    }
}

extern "C" void kernel_launch(void* const* d_in, const int* in_sizes, int n_in,
                              void* d_out, int out_size, void* d_ws, size_t ws_size,
                              hipStream_t stream) {
    const float* x         = (const float*)d_in[0];
    const float* omega     = (const float*)d_in[1];
    const float* raw_alpha = (const float*)d_in[2];
    const float* b_real    = (const float*)d_in[3];
    const float* b_imag    = (const float*)d_in[4];
    const float* W1        = (const float*)d_in[5];
    const float* b1        = (const float*)d_in[6];
    const float* W2        = (const float*)d_in[7];
    const float* b2        = (const float*)d_in[8];

    float* out = (float*)d_out;

    const long long NOUT = (long long)BB * LL * DD;
    const bool cplx = ((long long)out_size == 2 * NOUT);

    // scratch: ps (2 MiB) | hin (1 MiB) | ctr (32 B)
    const size_t PS_BYTES  = (size_t)NC * BD * sizeof(float4);
    const size_t HIN_BYTES = (size_t)NC * BD * sizeof(float2);
    const size_t CTR_BYTES = BB * sizeof(unsigned int);

    if (ws_size >= PS_BYTES + HIN_BYTES + CTR_BYTES) {
        float4* ps        = (float4*)d_ws;
        float2* hin       = (float2*)((char*)d_ws + PS_BYTES);
        unsigned int* ctr = (unsigned int*)((char*)d_ws + PS_BYTES + HIN_BYTES);

        hipMemsetAsync(ctr, 0, CTR_BYTES, stream);   // graph-capturable
        reduce_carry_kernel<<<NBLK, 256, 0, stream>>>(
            x, omega, raw_alpha, b_real, b_imag, W1, b1, W2, b2, ps, hin, ctr);
        if (cplx) {
            expand2_kernel<true><<<NBLK, 256, 0, stream>>>(
                x, omega, raw_alpha, b_real, b_imag, W1, b1, W2, b2, hin, out);
        } else {
            expand2_kernel<false><<<NBLK, 256, 0, stream>>>(
                x, omega, raw_alpha, b_real, b_imag, W1, b1, W2, b2, hin, out);
        }
    } else {
        if (cplx) {
            fallback_kernel<true><<<BB, 64, 0, stream>>>(
                x, omega, raw_alpha, b_real, b_imag, W1, b1, W2, b2, out);
        } else {
            fallback_kernel<false><<<BB, 64, 0, stream>>>(
                x, omega, raw_alpha, b_real, b_imag, W1, b1, W2, b2, out);
        }
    }
}

// Round 10
// 135.226 us; speedup vs baseline: 2.3811x; 1.4681x over previous
//
#include <hip/hip_runtime.h>
#include <math.h>

#define BB 8
#define LL 32768
#define DD 64
#define GH 16
#define TC 128
#define NC (LL / TC)          /* 256 chunks per sequence */
#define BD (BB * DD)          /* 512 chains */
#define WIN 16
#define PAD 8
#define WPB 4                 /* waves per block */
#define NBLK (BB * NC / WPB)  /* 512 blocks */

typedef float f32x2 __attribute__((ext_vector_type(2)));

__device__ __forceinline__ float sig_(float z) { return 1.0f / (1.0f + expf(-z)); }

__device__ __forceinline__ float raw_gate(float xv, const float* w1, const float* bb1,
                                          const float* w2, float bb2) {
    float h = bb2;
#pragma unroll
    for (int i = 0; i < GH; i++) {
        const float z = xv * w1[i] + bb1[i];
        h += (z * sig_(z)) * w2[i];           // silu
    }
    return sig_(h);
}

__device__ __forceinline__ void chan_params(const float* omega, const float* raw_alpha,
                                            int d, float& ar, float& ai) {
    const float alpha = -log1pf(expf(raw_alpha[d]));  // -softplus
    const float r = expf(alpha);
    ar = r * cosf(omega[d]);
    ai = r * sinf(omega[d]);
}

// Stage smoothed gate + x for chunk (b, t0) into this wave's LDS slices.
// Wave-synchronous (each wave owns its slice; no __syncthreads needed).
__device__ __forceinline__ void stage_gate_x(
        const float* __restrict__ x, int b, int t0, int lane,
        const float* __restrict__ W1, const float* __restrict__ b1,
        const float* __restrict__ W2, const float* __restrict__ b2,
        float* __restrict__ sraw, float* __restrict__ gsm, float* __restrict__ xt) {
    float w1[GH], bb1[GH], w2[GH];
#pragma unroll
    for (int i = 0; i < GH; i++) { w1[i] = W1[i]; bb1[i] = b1[i]; w2[i] = W2[i]; }
    const float bb2 = b2[0];
    for (int j = lane; j < TC + WIN; j += 64) {
        int idx = t0 - PAD + j;
        if (idx < 0)   idx = -idx;               // reflect (edge-excluding)
        if (idx >= LL) idx = 2 * LL - 2 - idx;
        const float xv = x[b * LL + idx];
        sraw[j] = raw_gate(xv, w1, bb1, w2, bb2);
        if (j >= PAD && j < PAD + TC) xt[j - PAD] = xv;
    }
    for (int i = lane; i < TC; i += 64) {
        float acc = 0.0f;
#pragma unroll
        for (int k = 0; k < WIN; k++) acc += sraw[i + k];
        gsm[i] = acc * (1.0f / WIN);
    }
}

// ---------- K1: per-chunk composites only (no fence, no atomics) ----------
// ps layout [c][chain]: coalesced write here, coalesced read in K2.
__global__ __launch_bounds__(256) void reduce_kernel(
        const float* __restrict__ x,
        const float* __restrict__ omega, const float* __restrict__ raw_alpha,
        const float* __restrict__ b_real, const float* __restrict__ b_imag,
        const float* __restrict__ W1, const float* __restrict__ b1,
        const float* __restrict__ W2, const float* __restrict__ b2,
        float4* __restrict__ ps) {
    __shared__ float sraw[WPB][TC + WIN];
    __shared__ float gsm[WPB][TC];
    __shared__ float xt[WPB][TC];

    const int tid  = threadIdx.x;
    const int lane = tid & 63;
    const int wv   = tid >> 6;
    const int u    = blockIdx.x * WPB + wv;   // (b, c)
    const int b    = u / NC;
    const int c    = u & (NC - 1);
    const int t0   = c * TC;

    stage_gate_x(x, b, t0, lane, W1, b1, W2, b2, sraw[wv], gsm[wv], xt[wv]);

    float ar, ai;
    chan_params(omega, raw_alpha, lane, ar, ai);
    const float br = b_real[lane], bi = b_imag[lane];

    float Pr = 1.0f, Pi = 0.0f, Sr = 0.0f, Si = 0.0f;
#pragma unroll 4
    for (int t = 0; t < TC; t++) {
        const float g  = gsm[wv][t];
        const float xv = xt[wv][t];
        const float cr = g * ar, ci = g * ai;
        const float nPr = cr * Pr - ci * Pi;
        const float nPi = cr * Pi + ci * Pr;
        const float nSr = cr * Sr - ci * Si + br * xv;
        const float nSi = cr * Si + ci * Sr + bi * xv;
        Pr = nPr; Pi = nPi; Sr = nSr; Si = nSi;
    }
    ps[c * BD + b * DD + lane] = make_float4(Pr, Pi, Sr, Si);
}

// ---------- K2: self-service prefix + expand (no fence; boundary = sync) ----------
template <bool CPLX>
__global__ __launch_bounds__(256) void expand_fused_kernel(
        const float* __restrict__ x,
        const float* __restrict__ omega, const float* __restrict__ raw_alpha,
        const float* __restrict__ b_real, const float* __restrict__ b_imag,
        const float* __restrict__ W1, const float* __restrict__ b1,
        const float* __restrict__ W2, const float* __restrict__ b2,
        const float4* __restrict__ ps, float* __restrict__ out) {
    __shared__ float sraw[WPB][TC + WIN];
    __shared__ float gsm[WPB][TC];
    __shared__ float xt[WPB][TC];

    const int tid  = threadIdx.x;
    const int lane = tid & 63;
    const int wv   = tid >> 6;
    const int u    = blockIdx.x * WPB + wv;   // (b, c)
    const int b    = u / NC;
    const int c    = u & (NC - 1);
    const int t0   = c * TC;

    stage_gate_x(x, b, t0, lane, W1, b1, W2, b2, sraw[wv], gsm[wv], xt[wv]);

    float ar, ai;
    chan_params(omega, raw_alpha, lane, ar, ai);
    const float br = b_real[lane], bi = b_imag[lane];

    // incoming state: compose chunks 0..c-1 of this chain (wave-uniform trip count,
    // coalesced 1KB reads, L2-resident). h = P_j*h + S_j applied in time order.
    float hr = 0.0f, hi = 0.0f;
    {
        const float4* pc = ps + b * DD + lane;
#pragma unroll 4
        for (int j = 0; j < c; j++) {
            const float4 v = pc[j * BD];
            const float nhr = v.x * hr - v.y * hi + v.z;
            const float nhi = v.x * hi + v.y * hr + v.w;
            hr = nhr; hi = nhi;
        }
    }

    size_t e = (size_t)(b * LL + t0) * DD + lane;
#pragma unroll 4
    for (int t = 0; t < TC; t++) {
        const float g  = gsm[wv][t];
        const float xv = xt[wv][t];
        const float cr = g * ar, ci = g * ai;
        const float nhr = cr * hr - ci * hi + br * xv;
        const float nhi = cr * hi + ci * hr + bi * xv;
        hr = nhr; hi = nhi;
        if constexpr (CPLX) {
            f32x2 val; val.x = hr; val.y = hi;
            __builtin_nontemporal_store(val, (f32x2*)out + e);
        } else {
            __builtin_nontemporal_store(hr, out + e);
        }
        e += DD;
    }
}

// ---------- zero-scratch serial fallback (insurance) ----------
template <bool CPLX>
__global__ __launch_bounds__(64) void fallback_kernel(
        const float* __restrict__ x,
        const float* __restrict__ omega, const float* __restrict__ raw_alpha,
        const float* __restrict__ b_real, const float* __restrict__ b_imag,
        const float* __restrict__ W1, const float* __restrict__ b1,
        const float* __restrict__ W2, const float* __restrict__ b2,
        float* __restrict__ out) {
    const int b = blockIdx.x;
    const int d = threadIdx.x;

    __shared__ float xtile[64];
    __shared__ float sraw[64 + WIN];
    __shared__ float gsm[64];

    float w1[GH], bb1[GH], w2[GH];
#pragma unroll
    for (int i = 0; i < GH; i++) { w1[i] = W1[i]; bb1[i] = b1[i]; w2[i] = W2[i]; }
    const float bb2 = b2[0];

    float ar, ai;
    chan_params(omega, raw_alpha, d, ar, ai);
    const float br = b_real[d], bi = b_imag[d];

    float hr = 0.0f, hi = 0.0f;
    for (int t0 = 0; t0 < LL; t0 += 64) {
        __syncthreads();
        for (int j = threadIdx.x; j < 64 + WIN; j += 64) {
            int idx = t0 - PAD + j;
            if (idx < 0)   idx = -idx;
            if (idx >= LL) idx = 2 * LL - 2 - idx;
            sraw[j] = raw_gate(x[b * LL + idx], w1, bb1, w2, bb2);
        }
        xtile[threadIdx.x] = x[b * LL + t0 + threadIdx.x];
        __syncthreads();
        float acc = 0.0f;
#pragma unroll
        for (int k = 0; k < WIN; k++) acc += sraw[threadIdx.x + k];
        gsm[threadIdx.x] = acc * (1.0f / WIN);
        __syncthreads();
        for (int tt = 0; tt < 64; tt++) {
            const float g  = gsm[tt];
            const float xv = xtile[tt];
            const float cr = g * ar, ci = g * ai;
            const float nhr = cr * hr - ci * hi + br * xv;
            const float nhi = cr * hi + ci * hr + bi * xv;
            hr = nhr; hi = nhi;
            const size_t e = (size_t)(b * LL + t0 + tt) * DD + d;
            if constexpr (CPLX) {
                f32x2 val; val.x = hr; val.y = hi;
                ((f32x2*)out)[e] = val;
            } else {
                out[e] = hr;
            }
        }
    }
}

extern "C" void kernel_launch(void* const* d_in, const int* in_sizes, int n_in,
                              void* d_out, int out_size, void* d_ws, size_t ws_size,
                              hipStream_t stream) {
    const float* x         = (const float*)d_in[0];
    const float* omega     = (const float*)d_in[1];
    const float* raw_alpha = (const float*)d_in[2];
    const float* b_real    = (const float*)d_in[3];
    const float* b_imag    = (const float*)d_in[4];
    const float* W1        = (const float*)d_in[5];
    const float* b1        = (const float*)d_in[6];
    const float* W2        = (const float*)d_in[7];
    const float* b2        = (const float*)d_in[8];

    float* out = (float*)d_out;

    const long long NOUT = (long long)BB * LL * DD;
    const bool cplx = ((long long)out_size == 2 * NOUT);

    const size_t PS_BYTES = (size_t)NC * BD * sizeof(float4);   // 2 MiB

    if (ws_size >= PS_BYTES) {
        float4* ps = (float4*)d_ws;
        reduce_kernel<<<NBLK, 256, 0, stream>>>(
            x, omega, raw_alpha, b_real, b_imag, W1, b1, W2, b2, ps);
        if (cplx) {
            expand_fused_kernel<true><<<NBLK, 256, 0, stream>>>(
                x, omega, raw_alpha, b_real, b_imag, W1, b1, W2, b2, ps, out);
        } else {
            expand_fused_kernel<false><<<NBLK, 256, 0, stream>>>(
                x, omega, raw_alpha, b_real, b_imag, W1, b1, W2, b2, ps, out);
        }
    } else {
        if (cplx) {
            fallback_kernel<true><<<BB, 64, 0, stream>>>(
                x, omega, raw_alpha, b_real, b_imag, W1, b1, W2, b2, out);
        } else {
            fallback_kernel<false><<<BB, 64, 0, stream>>>(
                x, omega, raw_alpha, b_real, b_imag, W1, b1, W2, b2, out);
        }
    }
}

// Round 11
// 134.177 us; speedup vs baseline: 2.3997x; 1.0078x over previous
//
#include <hip/hip_runtime.h>
#include <math.h>

#define BB 8
#define LL 32768
#define DD 64
#define GH 16
#define TC 128
#define NC (LL / TC)          /* 256 chunks per sequence */
#define BD (BB * DD)          /* 512 chains */
#define WIN 16
#define PAD 8
#define WPB 4                 /* waves per block */
#define NBLK (BB * NC / WPB)  /* 512 blocks */

typedef float f32x2 __attribute__((ext_vector_type(2)));

__device__ __forceinline__ float sig_(float z) { return 1.0f / (1.0f + expf(-z)); }

__device__ __forceinline__ float rdlane(float v, int l) {
    return __int_as_float(__builtin_amdgcn_readlane(__float_as_int(v), l));
}

__device__ __forceinline__ float raw_gate(float xv, const float* w1, const float* bb1,
                                          const float* w2, float bb2) {
    float h = bb2;
#pragma unroll
    for (int i = 0; i < GH; i++) {
        const float z = xv * w1[i] + bb1[i];
        h += (z * sig_(z)) * w2[i];           // silu
    }
    return sig_(h);
}

__device__ __forceinline__ void chan_params(const float* omega, const float* raw_alpha,
                                            int d, float& ar, float& ai) {
    const float alpha = -log1pf(expf(raw_alpha[d]));  // -softplus
    const float r = expf(alpha);
    ar = r * cosf(omega[d]);
    ai = r * sinf(omega[d]);
}

// Stage chunk (b,t0): smoothed gate + x into per-lane REGISTERS:
// lane j ends with g0/x0 for t=t0+j, g1/x1 for t=t0+64+j.
// LDS (per wave slice) used only to build the box filter. Wave-synchronous.
__device__ __forceinline__ void stage_regs(
        const float* __restrict__ x, int b, int t0, int lane,
        const float* __restrict__ W1, const float* __restrict__ b1,
        const float* __restrict__ W2, const float* __restrict__ b2,
        float* __restrict__ sraw, float* __restrict__ sx,
        float& g0, float& g1, float& x0, float& x1) {
    float w1[GH], bb1[GH], w2[GH];
#pragma unroll
    for (int i = 0; i < GH; i++) { w1[i] = W1[i]; bb1[i] = b1[i]; w2[i] = W2[i]; }
    const float bb2 = b2[0];
#pragma unroll
    for (int j = lane; j < TC + WIN; j += 64) {
        int idx = t0 - PAD + j;
        if (idx < 0)   idx = -idx;               // reflect (edge-excluding)
        if (idx >= LL) idx = 2 * LL - 2 - idx;
        const float xv = x[b * LL + idx];
        sx[j]   = xv;
        sraw[j] = raw_gate(xv, w1, bb1, w2, bb2);
    }
    float a0 = 0.0f, a1 = 0.0f;
#pragma unroll
    for (int k = 0; k < WIN; k++) {
        a0 += sraw[lane + k];                    // stride-1: 2-way alias, free
        a1 += sraw[lane + 64 + k];
    }
    g0 = a0 * (1.0f / WIN);
    g1 = a1 * (1.0f / WIN);
    x0 = sx[lane + PAD];
    x1 = sx[lane + 64 + PAD];
}

// ---------- K1: per-chunk composites (register scan, no fences) ----------
__global__ __launch_bounds__(256) void reduce_kernel(
        const float* __restrict__ x,
        const float* __restrict__ omega, const float* __restrict__ raw_alpha,
        const float* __restrict__ b_real, const float* __restrict__ b_imag,
        const float* __restrict__ W1, const float* __restrict__ b1,
        const float* __restrict__ W2, const float* __restrict__ b2,
        float4* __restrict__ ps) {
    __shared__ float sraw[WPB][TC + WIN];
    __shared__ float sx[WPB][TC + WIN];

    const int tid  = threadIdx.x;
    const int lane = tid & 63;
    const int wv   = tid >> 6;
    const int u    = blockIdx.x * WPB + wv;   // (b, c)
    const int b    = u / NC;
    const int c    = u & (NC - 1);
    const int t0   = c * TC;

    float g0, g1, x0, x1;
    stage_regs(x, b, t0, lane, W1, b1, W2, b2, sraw[wv], sx[wv], g0, g1, x0, x1);

    float ar, ai;
    chan_params(omega, raw_alpha, lane, ar, ai);
    const float br = b_real[lane], bi = b_imag[lane];

    float Pr = 1.0f, Pi = 0.0f, Sr = 0.0f, Si = 0.0f;
#pragma unroll
    for (int tt = 0; tt < 64; tt++) {
        const float g  = rdlane(g0, tt);
        const float xv = rdlane(x0, tt);
        const float cr = g * ar, ci = g * ai;
        const float nPr = cr * Pr - ci * Pi;
        const float nPi = cr * Pi + ci * Pr;
        const float nSr = cr * Sr - ci * Si + br * xv;
        const float nSi = cr * Si + ci * Sr + bi * xv;
        Pr = nPr; Pi = nPi; Sr = nSr; Si = nSi;
    }
#pragma unroll
    for (int tt = 0; tt < 64; tt++) {
        const float g  = rdlane(g1, tt);
        const float xv = rdlane(x1, tt);
        const float cr = g * ar, ci = g * ai;
        const float nPr = cr * Pr - ci * Pi;
        const float nPi = cr * Pi + ci * Pr;
        const float nSr = cr * Sr - ci * Si + br * xv;
        const float nSi = cr * Si + ci * Sr + bi * xv;
        Pr = nPr; Pi = nPi; Sr = nSr; Si = nSi;
    }
    ps[c * BD + b * DD + lane] = make_float4(Pr, Pi, Sr, Si);
}

// ---------- K2: self-service prefix + register-scan expand ----------
template <bool CPLX>
__global__ __launch_bounds__(256) void expand_fused_kernel(
        const float* __restrict__ x,
        const float* __restrict__ omega, const float* __restrict__ raw_alpha,
        const float* __restrict__ b_real, const float* __restrict__ b_imag,
        const float* __restrict__ W1, const float* __restrict__ b1,
        const float* __restrict__ W2, const float* __restrict__ b2,
        const float4* __restrict__ ps, float* __restrict__ out) {
    __shared__ float sraw[WPB][TC + WIN];
    __shared__ float sx[WPB][TC + WIN];

    const int tid  = threadIdx.x;
    const int lane = tid & 63;
    const int wv   = tid >> 6;
    const int u    = blockIdx.x * WPB + wv;   // (b, c)
    const int b    = u / NC;
    const int c    = u & (NC - 1);
    const int t0   = c * TC;

    float g0, g1, x0, x1;
    stage_regs(x, b, t0, lane, W1, b1, W2, b2, sraw[wv], sx[wv], g0, g1, x0, x1);

    float ar, ai;
    chan_params(omega, raw_alpha, lane, ar, ai);
    const float br = b_real[lane], bi = b_imag[lane];

    // incoming state: compose composites of chunks 0..c-1 (coalesced, L2-hot,
    // independent loads -> pipelined; compose chain is cheap FMA)
    float hr = 0.0f, hi = 0.0f;
    {
        const float4* pc = ps + b * DD + lane;
#pragma unroll 4
        for (int j = 0; j < c; j++) {
            const float4 v = pc[j * BD];
            const float nhr = v.x * hr - v.y * hi + v.z;
            const float nhi = v.x * hi + v.y * hr + v.w;
            hr = nhr; hi = nhi;
        }
    }

    size_t e = (size_t)(b * LL + t0) * DD + lane;
#pragma unroll
    for (int tt = 0; tt < 64; tt++) {
        const float g  = rdlane(g0, tt);
        const float xv = rdlane(x0, tt);
        const float cr = g * ar, ci = g * ai;
        const float nhr = cr * hr - ci * hi + br * xv;
        const float nhi = cr * hi + ci * hr + bi * xv;
        hr = nhr; hi = nhi;
        if constexpr (CPLX) {
            f32x2 val; val.x = hr; val.y = hi;
            __builtin_nontemporal_store(val, (f32x2*)out + e);
        } else {
            __builtin_nontemporal_store(hr, out + e);
        }
        e += DD;
    }
#pragma unroll
    for (int tt = 0; tt < 64; tt++) {
        const float g  = rdlane(g1, tt);
        const float xv = rdlane(x1, tt);
        const float cr = g * ar, ci = g * ai;
        const float nhr = cr * hr - ci * hi + br * xv;
        const float nhi = cr * hi + ci * hr + bi * xv;
        hr = nhr; hi = nhi;
        if constexpr (CPLX) {
            f32x2 val; val.x = hr; val.y = hi;
            __builtin_nontemporal_store(val, (f32x2*)out + e);
        } else {
            __builtin_nontemporal_store(hr, out + e);
        }
        e += DD;
    }
}

// ---------- zero-scratch serial fallback (insurance) ----------
template <bool CPLX>
__global__ __launch_bounds__(64) void fallback_kernel(
        const float* __restrict__ x,
        const float* __restrict__ omega, const float* __restrict__ raw_alpha,
        const float* __restrict__ b_real, const float* __restrict__ b_imag,
        const float* __restrict__ W1, const float* __restrict__ b1,
        const float* __restrict__ W2, const float* __restrict__ b2,
        float* __restrict__ out) {
    const int b = blockIdx.x;
    const int d = threadIdx.x;

    __shared__ float xtile[64];
    __shared__ float sraw[64 + WIN];
    __shared__ float gsm[64];

    float w1[GH], bb1[GH], w2[GH];
#pragma unroll
    for (int i = 0; i < GH; i++) { w1[i] = W1[i]; bb1[i] = b1[i]; w2[i] = W2[i]; }
    const float bb2 = b2[0];

    float ar, ai;
    chan_params(omega, raw_alpha, d, ar, ai);
    const float br = b_real[d], bi = b_imag[d];

    float hr = 0.0f, hi = 0.0f;
    for (int t0 = 0; t0 < LL; t0 += 64) {
        __syncthreads();
        for (int j = threadIdx.x; j < 64 + WIN; j += 64) {
            int idx = t0 - PAD + j;
            if (idx < 0)   idx = -idx;
            if (idx >= LL) idx = 2 * LL - 2 - idx;
            sraw[j] = raw_gate(x[b * LL + idx], w1, bb1, w2, bb2);
        }
        xtile[threadIdx.x] = x[b * LL + t0 + threadIdx.x];
        __syncthreads();
        float acc = 0.0f;
#pragma unroll
        for (int k = 0; k < WIN; k++) acc += sraw[threadIdx.x + k];
        gsm[threadIdx.x] = acc * (1.0f / WIN);
        __syncthreads();
        for (int tt = 0; tt < 64; tt++) {
            const float g  = gsm[tt];
            const float xv = xtile[tt];
            const float cr = g * ar, ci = g * ai;
            const float nhr = cr * hr - ci * hi + br * xv;
            const float nhi = cr * hi + ci * hr + bi * xv;
            hr = nhr; hi = nhi;
            const size_t e = (size_t)(b * LL + t0 + tt) * DD + d;
            if constexpr (CPLX) {
                f32x2 val; val.x = hr; val.y = hi;
                ((f32x2*)out)[e] = val;
            } else {
                out[e] = hr;
            }
        }
    }
}

extern "C" void kernel_launch(void* const* d_in, const int* in_sizes, int n_in,
                              void* d_out, int out_size, void* d_ws, size_t ws_size,
                              hipStream_t stream) {
    const float* x         = (const float*)d_in[0];
    const float* omega     = (const float*)d_in[1];
    const float* raw_alpha = (const float*)d_in[2];
    const float* b_real    = (const float*)d_in[3];
    const float* b_imag    = (const float*)d_in[4];
    const float* W1        = (const float*)d_in[5];
    const float* b1        = (const float*)d_in[6];
    const float* W2        = (const float*)d_in[7];
    const float* b2        = (const float*)d_in[8];

    float* out = (float*)d_out;

    const long long NOUT = (long long)BB * LL * DD;
    const bool cplx = ((long long)out_size == 2 * NOUT);

    const size_t PS_BYTES = (size_t)NC * BD * sizeof(float4);   // 2 MiB

    if (ws_size >= PS_BYTES) {
        float4* ps = (float4*)d_ws;
        reduce_kernel<<<NBLK, 256, 0, stream>>>(
            x, omega, raw_alpha, b_real, b_imag, W1, b1, W2, b2, ps);
        if (cplx) {
            expand_fused_kernel<true><<<NBLK, 256, 0, stream>>>(
                x, omega, raw_alpha, b_real, b_imag, W1, b1, W2, b2, ps, out);
        } else {
            expand_fused_kernel<false><<<NBLK, 256, 0, stream>>>(
                x, omega, raw_alpha, b_real, b_imag, W1, b1, W2, b2, ps, out);
        }
    } else {
        if (cplx) {
            fallback_kernel<true><<<BB, 64, 0, stream>>>(
                x, omega, raw_alpha, b_real, b_imag, W1, b1, W2, b2, out);
        } else {
            fallback_kernel<false><<<BB, 64, 0, stream>>>(
                x, omega, raw_alpha, b_real, b_imag, W1, b1, W2, b2, out);
        }
    }
}